// Round 3
// baseline (201.093 us; speedup 1.0000x reference)
//
#include <hip/hip_runtime.h>

#define DDIM 256
#define NTOK 4096   // B*S = 64*64
#define NEGN 8192
// small 64x64 kernel (fr alignment)
#define TM 64
#define TN 64
#define LDT 40      // padded halfs per LDS row for the small kernel

typedef __attribute__((ext_vector_type(8))) short bf16x8;
typedef __attribute__((ext_vector_type(4))) float f32x4;

__device__ inline unsigned short f2bf(float f) {
    unsigned int u = __float_as_uint(f);
    unsigned int r = u + 0x7FFFu + ((u >> 16) & 1u);
    return (unsigned short)(r >> 16);
}

// global->LDS direct DMA, 16B/lane; LDS dest = wave-uniform base + lane*16.
__device__ inline void gl_lds16(const unsigned short* g, unsigned short* l) {
    __builtin_amdgcn_global_load_lds(
        reinterpret_cast<__attribute__((address_space(1))) unsigned int*>(
            reinterpret_cast<uintptr_t>(g)),
        reinterpret_cast<__attribute__((address_space(3))) unsigned int*>(
            reinterpret_cast<uintptr_t>(l)),
        16, 0, 0);
}

__device__ inline void wait_vmcnt0() { asm volatile("s_waitcnt vmcnt(0)" ::: "memory"); }
__device__ inline void raw_barrier() { asm volatile("s_barrier" ::: "memory"); }

// DPP 16-lane sum reduction — VALU only.
template<int CTRL>
__device__ inline float dpp_add(float x) {
    int v = __builtin_amdgcn_update_dpp(0, __float_as_int(x), CTRL, 0xF, 0xF, false);
    return x + __int_as_float(v);
}
__device__ inline float red16(float x) {
    x = dpp_add<0xB1>(x);    // quad_perm [1,0,3,2]
    x = dpp_add<0x4E>(x);    // quad_perm [2,3,0,1]
    x = dpp_add<0x141>(x);   // row_half_mirror
    x = dpp_add<0x140>(x);   // row_mirror
    return x;
}

// ---------------------------------------------------------------------------
// Kernel 1: gather + fp32->bf16 convert + fused en_score + denom zero-init.
// (unchanged from the 202 us baseline)
// ---------------------------------------------------------------------------
__global__ void gather_kernel(
    const float* __restrict__ zs,
    const float* __restrict__ W_en, const float* __restrict__ W_fr,
    const int* __restrict__ pos_en, const int* __restrict__ neg_en,
    const int* __restrict__ pos_fr, const int* __restrict__ neg_fr,
    const int* __restrict__ x_en,
    unsigned short* __restrict__ z_bf,
    unsigned short* __restrict__ E_en, unsigned short* __restrict__ E_fr,
    float* __restrict__ en_score,
    float* __restrict__ denom_en, float* __restrict__ denom_fr,
    int Pe, int Pf, int Lpe, int Lpf)
{
    int row  = blockIdx.x * 4 + (threadIdx.x >> 6);
    int lane = threadIdx.x & 63;
    const float* src = nullptr;
    unsigned short* dst = nullptr;
    bool zero = false;

    if (row < NTOK) {
        src = zs + (size_t)row * DDIM;
        dst = z_bf + (size_t)row * DDIM;
        if (lane == 0) { denom_en[row] = 0.0f; denom_fr[row] = 0.0f; }
    } else if (row < NTOK + Lpe) {
        int j = row - NTOK;
        int Le = Pe + NEGN;
        int idx = 0;
        if (j < Pe)      idx = pos_en[j];
        else if (j < Le) idx = neg_en[j - Pe];
        else             zero = true;
        src = W_en + (size_t)idx * DDIM;
        dst = E_en + (size_t)j * DDIM;
    } else if (row < NTOK + Lpe + Lpf) {
        int j = row - NTOK - Lpe;
        int Lf = Pf + NEGN;
        int idx = 0;
        if (j < Pf)      idx = pos_fr[j];
        else if (j < Lf) idx = neg_fr[j - Pf];
        else             zero = true;
        src = W_fr + (size_t)idx * DDIM;
        dst = E_fr + (size_t)j * DDIM;
    } else if (row < NTOK + Lpe + Lpf + NTOK) {
        // fused en_score: zs[j] . W_en[x_en[j]] in fp32, wave reduce
        int j = row - NTOK - Lpe - Lpf;
        int idx = x_en[j];
        float4 z = *(const float4*)(zs   + (size_t)j   * DDIM + lane * 4);
        float4 w = *(const float4*)(W_en + (size_t)idx * DDIM + lane * 4);
        float s = z.x * w.x + z.y * w.y + z.z * w.z + z.w * w.w;
        #pragma unroll
        for (int m = 32; m; m >>= 1) s += __shfl_xor(s, m);
        if (lane == 0) en_score[j] = s;
        return;
    } else {
        return;
    }

    int d = lane * 4;
    float4 v;
    if (zero) { v.x = v.y = v.z = v.w = 0.0f; }
    else      { v = *(const float4*)(src + d); }
    ushort4 o;
    o.x = f2bf(v.x); o.y = f2bf(v.y); o.z = f2bf(v.z); o.w = f2bf(v.w);
    *(ushort4*)(dst + d) = o;
}

// ---------------------------------------------------------------------------
// Kernel 2: fused denominators — DE-PHASED PIPELINES.
// R2 post-mortem: MfmaUtil 35 + VALUBusy 30 = 65% => 35% of cycles NEITHER
// pipe issues, because the 4-wave block barrier phase-locks all resident
// waves into [MFMA burst] then [exp epilogue burst]; pipes alternate instead
// of overlapping. Fix: shrink the sync domain — 1024 blocks of 128 threads
// (2 waves), each an independent pipeline over a 32-row n-strip (2-wave
// shared staging, 16 KB tile double-buffered = 32 KB LDS). 4 blocks/CU =
// 4 naturally staggered pipelines: one block's epilogue overlaps another's
// MFMA burst (m114 co-scheduling). Still 8 waves/CU; E re-reads (x32 vs x16
// m-readers) stay L2-resident (~1.4 TB/s/XCD << ceiling). Sync protocol per
// tile unchanged from R2 (own vmcnt(0) drain -> raw s_barrier), HW-verified
// absmax 0.0.
// Frag layouts (HW-verified): A/B lane holds row (lane&15), 8 k-halfs at
// (lane>>4)*8;  C/D: n-col = lane&15, m-row = (lane>>4)*4 + reg.
// ---------------------------------------------------------------------------
__global__ __launch_bounds__(128, 2) void expsum_stream(
    const unsigned short* __restrict__ A,   // z_bf [4096 x 256]
    const unsigned short* __restrict__ E,   // [Ltot x 256]
    const float* __restrict__ kep, const float* __restrict__ kfp,
    float* __restrict__ out_en, float* __restrict__ out_fr,
    int Pe, int Pf, int Lpe, int NT)        // NT = Ltot/32 n-tiles (32-row)
{
    // 2 tile-buffers x 8 chunks x (32 rows x 32 k bf16 = 2048 B).
    // Chunk slab: 2 sub-blocks of 16 rows, lane-linear (lane*16B) each —
    // conflict-free DMA write + b128 read.
    __shared__ __align__(16) unsigned short Bs[2][8][1024];

    // 1024 blocks: xcd = lin&7, slice sl = xcd + 8*((lin>>3)&3) in [0,32),
    // m-granule mg = lin>>5 in [0,32) (128 rows; wave owns 64).
    // XCD k streams only 32-row tiles ≡ k (mod 8) -> 1/8 of E L2-resident.
    int lin = blockIdx.y * 64 + blockIdx.x;
    int xcd = lin & 7;
    int sl  = xcd + 8 * ((lin >> 3) & 3);
    int mg  = lin >> 5;

    int t    = threadIdx.x;
    int lane = t & 63;
    int wave = t >> 6;          // 0..1
    int col  = lane & 15;
    int quad = lane >> 4;

    // kappas: load + pin BEFORE any DMA so the vmcnt queue stays clean
    float ke = kep[0], kf = kfp[0];
    asm volatile("" : "+v"(ke), "+v"(kf) : : "memory");

    // ---- A fragments in registers (one-time load; wave owns 64 m rows)
    bf16x8 afr[4][8];
    {
        const unsigned short* Ap =
            A + ((size_t)(mg * 128 + wave * 64 + col)) * DDIM + quad * 8;
        #pragma unroll
        for (int i = 0; i < 4; i++)
            #pragma unroll
            for (int c = 0; c < 8; c++)
                afr[i][c] = *(const bf16x8*)(Ap + (size_t)i * 16 * DDIM + c * 32);
    }

    float sums[4][4];
    #pragma unroll
    for (int i = 0; i < 4; i++)
        #pragma unroll
        for (int rr = 0; rr < 4; rr++) sums[i][rr] = 0.0f;
    float* curout = out_en;
    int outrow = mg * 128 + wave * 64;

    int ntiles = (NT - sl + 31) >> 5;

    // stage tile s: this wave's 16-row sub-block for ALL 8 k-chunks (8 DMAs).
    #define STAGE_TILE(s) do {                                               \
        int tl_ = sl + ((s) << 5);                                           \
        const unsigned short* g_ =                                           \
            E + (size_t)(tl_ * 32 + wave * 16 + col) * DDIM + quad * 8;      \
        unsigned short* l_ = &Bs[(s) & 1][0][wave * 512];                    \
        _Pragma("unroll")                                                    \
        for (int kc_ = 0; kc_ < 8; kc_++)                                    \
            gl_lds16(g_ + kc_ * 32, l_ + kc_ * 1024);                        \
    } while (0)

    STAGE_TILE(0);

    for (int s = 0; s < ntiles; s++) {
        int tl = sl + (s << 5);
        int nb = tl * 32;

        wait_vmcnt0();      // my tile-s DMAs retired (issued 1 tile-period ago)
        raw_barrier();      // both waves' tile-s resident; both done reading s-1

        if (s + 1 < ntiles) STAGE_TILE(s + 1);   // 8 DMAs, fly under compute

        float* o = (nb >= Lpe) ? out_fr : out_en;
        if (o != curout) {
            // flush en sums at the en->fr boundary (stream is monotone);
            // atomics retire behind tile s+1's DMAs, drained next iter.
            #pragma unroll
            for (int i = 0; i < 4; i++)
                #pragma unroll
                for (int rr = 0; rr < 4; rr++) {
                    float v = red16(sums[i][rr]);
                    if (col == 0)
                        atomicAdd(curout + outrow + 16 * i + quad * 4 + rr, v);
                    sums[i][rr] = 0.0f;
                }
            curout = o;
        }

        // arithmetic weights: n < P -> 1 ; n < P+NEGN -> kappa ; else 0 (pad)
        float wj[2];
        #pragma unroll
        for (int j = 0; j < 2; j++) {
            int ngl = nb + 16 * j + col;
            if (nb < Lpe) {
                wj[j] = (ngl < Pe) ? 1.0f : ((ngl < Pe + NEGN) ? ke : 0.0f);
            } else {
                int nl = ngl - Lpe;
                wj[j] = (nl < Pf) ? 1.0f : ((nl < Pf + NEGN) ? kf : 0.0f);
            }
        }

        f32x4 acc[4][2];
        #pragma unroll
        for (int i = 0; i < 4; i++)
            #pragma unroll
            for (int j = 0; j < 2; j++)
                acc[i][j] = (f32x4){0.f, 0.f, 0.f, 0.f};

        // 8 chunks, no syncs: compiler pipelines ds_reads across chunks.
        #pragma unroll
        for (int k8 = 0; k8 < 8; k8++) {
            bf16x8 bfv[2];
            #pragma unroll
            for (int j = 0; j < 2; j++)
                bfv[j] = *(const bf16x8*)(
                    &Bs[s & 1][k8][j * 512 + quad * 128 + col * 8]);
            #pragma unroll
            for (int j = 0; j < 2; j++)
                #pragma unroll
                for (int i = 0; i < 4; i++)
                    acc[i][j] = __builtin_amdgcn_mfma_f32_16x16x32_bf16(
                        afr[i][k8], bfv[j], acc[i][j], 0, 0, 0);
        }

        // per-tile epilogue: weighted exp only; column reduction deferred.
        #pragma unroll
        for (int i = 0; i < 4; i++)
            #pragma unroll
            for (int rr = 0; rr < 4; rr++) {
                sums[i][rr] += wj[0] * __expf(acc[i][0][rr])
                             + wj[1] * __expf(acc[i][1][rr]);
            }
    }
    #undef STAGE_TILE

    // final flush: one deferred 16-lane reduction per acc entry
    #pragma unroll
    for (int i = 0; i < 4; i++)
        #pragma unroll
        for (int rr = 0; rr < 4; rr++) {
            float v = red16(sums[i][rr]);
            if (col == 0)
                atomicAdd(curout + outrow + 16 * i + quad * 4 + rr, v);
        }
}

// ---------------------------------------------------------------------------
// Kernel 3: fr alignment (per-batch 64x64 exp-sum, weight 1/denom_fr) with
// inline W_fr[x_fr] gather+convert for A and the final loss fused in.
// (unchanged from the 202 us baseline)
// ---------------------------------------------------------------------------
__global__ __launch_bounds__(256) void expsum_gemm64_loss(
    const float* __restrict__ W_fr,         // [V_FR x 256] fp32
    const int* __restrict__ x_fr,           // [B*64]
    const unsigned short* __restrict__ Bm,  // z_bf  [B][64 x 256]
    const float* __restrict__ denom_fr,     // [B*64]
    const float* __restrict__ denom_en,     // [B*64]
    const float* __restrict__ en_score,     // [B*64]
    const float* __restrict__ en_mask,
    const float* __restrict__ fr_mask,
    float* __restrict__ outloss)            // [128]: en | fr
{
    __shared__ __align__(16) unsigned short lda[TM * LDT];
    __shared__ __align__(16) unsigned short ldb[TN * LDT];
    __shared__ float tbuf[64];

    int batch = blockIdx.x;
    const unsigned short* Bb = Bm + (size_t)batch * TN * DDIM;

    int t      = threadIdx.x;
    int srow   = t >> 2;
    int schunk = t & 3;
    int lane   = t & 63;
    int wave   = t >> 6;
    int col    = lane & 15;
    int quad   = lane >> 4;

    int aidx = x_fr[batch * 64 + srow];
    const float* Arow = W_fr + (size_t)aidx * DDIM;

    f32x4 acc0 = {0.f,0.f,0.f,0.f};
    f32x4 acc1 = {0.f,0.f,0.f,0.f};
    f32x4 acc2 = {0.f,0.f,0.f,0.f};
    f32x4 acc3 = {0.f,0.f,0.f,0.f};

    for (int kk = 0; kk < DDIM; kk += 32) {
        float4 f0 = *(const float4*)(Arow + kk + schunk * 8);
        float4 f1 = *(const float4*)(Arow + kk + schunk * 8 + 4);
        uint4 bv = *(const uint4*)(Bb + (size_t)srow * DDIM + kk + schunk * 8);
        ushort4 ua; ua.x = f2bf(f0.x); ua.y = f2bf(f0.y); ua.z = f2bf(f0.z); ua.w = f2bf(f0.w);
        ushort4 ub; ub.x = f2bf(f1.x); ub.y = f2bf(f1.y); ub.z = f2bf(f1.z); ub.w = f2bf(f1.w);
        __syncthreads();
        *(ushort4*)(lda + srow * LDT + schunk * 8)     = ua;
        *(ushort4*)(lda + srow * LDT + schunk * 8 + 4) = ub;
        *(uint4*)(ldb + srow * LDT + schunk * 8) = bv;
        __syncthreads();

        bf16x8 af = *(const bf16x8*)(lda + (wave * 16 + col) * LDT + quad * 8);
        bf16x8 b0 = *(const bf16x8*)(ldb + ( 0 + col) * LDT + quad * 8);
        bf16x8 b1 = *(const bf16x8*)(ldb + (16 + col) * LDT + quad * 8);
        bf16x8 b2 = *(const bf16x8*)(ldb + (32 + col) * LDT + quad * 8);
        bf16x8 b3 = *(const bf16x8*)(ldb + (48 + col) * LDT + quad * 8);
        acc0 = __builtin_amdgcn_mfma_f32_16x16x32_bf16(af, b0, acc0, 0, 0, 0);
        acc1 = __builtin_amdgcn_mfma_f32_16x16x32_bf16(af, b1, acc1, 0, 0, 0);
        acc2 = __builtin_amdgcn_mfma_f32_16x16x32_bf16(af, b2, acc2, 0, 0, 0);
        acc3 = __builtin_amdgcn_mfma_f32_16x16x32_bf16(af, b3, acc3, 0, 0, 0);
    }

    const float* db = denom_fr + batch * 64;
    float w0 = 1.0f / db[ 0 + col];
    float w1 = 1.0f / db[16 + col];
    float w2 = 1.0f / db[32 + col];
    float w3 = 1.0f / db[48 + col];

    float tot0 = w0 * __expf(acc0.x) + w1 * __expf(acc1.x) + w2 * __expf(acc2.x) + w3 * __expf(acc3.x);
    float tot1 = w0 * __expf(acc0.y) + w1 * __expf(acc1.y) + w2 * __expf(acc2.y) + w3 * __expf(acc3.y);
    float tot2 = w0 * __expf(acc0.z) + w1 * __expf(acc1.z) + w2 * __expf(acc2.z) + w3 * __expf(acc3.z);
    float tot3 = w0 * __expf(acc0.w) + w1 * __expf(acc1.w) + w2 * __expf(acc2.w) + w3 * __expf(acc3.w);

    #pragma unroll
    for (int m = 1; m < 16; m <<= 1) {
        tot0 += __shfl_xor(tot0, m);
        tot1 += __shfl_xor(tot1, m);
        tot2 += __shfl_xor(tot2, m);
        tot3 += __shfl_xor(tot3, m);
    }
    if (col == 0) {
        int base = wave * 16 + quad * 4;
        tbuf[base + 0] = tot0; tbuf[base + 1] = tot1;
        tbuf[base + 2] = tot2; tbuf[base + 3] = tot3;
    }
    __syncthreads();

    if (t < 64) {
        int i = batch * 64 + t;
        float a = (en_score[i] - __logf(denom_en[i])) * en_mask[i];
        float c = __logf(tbuf[t]) * fr_mask[i];
        #pragma unroll
        for (int m = 32; m; m >>= 1) { a += __shfl_xor(a, m); c += __shfl_xor(c, m); }
        if (t == 0) { outloss[batch] = a; outloss[64 + batch] = c; }
    }
}

extern "C" void kernel_launch(void* const* d_in, const int* in_sizes, int n_in,
                              void* d_out, int out_size, void* d_ws, size_t ws_size,
                              hipStream_t stream)
{
    const float* zs       = (const float*)d_in[0];
    const int*   x_en     = (const int*)d_in[1];
    const int*   x_fr     = (const int*)d_in[2];
    const float* en_mask  = (const float*)d_in[3];
    const float* fr_mask  = (const float*)d_in[4];
    const float* W_en     = (const float*)d_in[5];
    const float* W_fr     = (const float*)d_in[6];
    const int*   pos_en   = (const int*)d_in[7];
    const int*   neg_en   = (const int*)d_in[8];
    const int*   pos_fr   = (const int*)d_in[9];
    const int*   neg_fr   = (const int*)d_in[10];
    const float* kappa_en = (const float*)d_in[11];
    const float* kappa_fr = (const float*)d_in[12];

    int Pe  = in_sizes[7];
    int Pf  = in_sizes[9];
    int Lpe = (Pe + NEGN + 63) & ~63;     // 64-aligned (no 32-row straddle)
    int Lpf = (Pf + NEGN + 63) & ~63;
    int Ltot = Lpe + Lpf;
    int NT32 = Ltot / 32;                 // 32-row n-tiles

    char* w = (char*)d_ws;
    float* denom_en = (float*)w; w += NTOK * 4;
    float* denom_fr = (float*)w; w += NTOK * 4;
    float* en_score = (float*)w; w += NTOK * 4;
    unsigned short* z_bf  = (unsigned short*)w; w += (size_t)NTOK * DDIM * 2;
    unsigned short* E_all = (unsigned short*)w; w += (size_t)Ltot * DDIM * 2;

    int totrows = NTOK + Lpe + Lpf + NTOK;
    gather_kernel<<<(totrows + 3) / 4, 256, 0, stream>>>(
        zs, W_en, W_fr, pos_en, neg_en, pos_fr, neg_fr, x_en,
        z_bf, E_all, E_all + (size_t)Lpe * DDIM,
        en_score, denom_en, denom_fr, Pe, Pf, Lpe, Lpf);

    // fused denominators: 4 de-phased 2-wave pipelines per CU
    expsum_stream<<<dim3(64, 16), 128, 0, stream>>>(
        z_bf, E_all, kappa_en, kappa_fr, denom_en, denom_fr, Pe, Pf, Lpe, NT32);

    // fr alignment + inline W_fr gather + fused loss
    expsum_gemm64_loss<<<64, 256, 0, stream>>>(
        W_fr, x_fr, z_bf, denom_fr, denom_en, en_score, en_mask, fr_mask,
        (float*)d_out);
}

// Round 4
// 191.316 us; speedup vs baseline: 1.0511x; 1.0511x over previous
//
#include <hip/hip_runtime.h>

#define DDIM 256
#define NTOK 4096   // B*S = 64*64
#define NEGN 8192
#define LOG2E 1.4426950408889634f
// small 64x64 kernel (fr alignment)
#define TM 64
#define TN 64
#define LDT 40      // padded halfs per LDS row for the small kernel

typedef __attribute__((ext_vector_type(8))) short bf16x8;
typedef __attribute__((ext_vector_type(4))) float f32x4;

__device__ inline unsigned short f2bf(float f) {
    unsigned int u = __float_as_uint(f);
    unsigned int r = u + 0x7FFFu + ((u >> 16) & 1u);
    return (unsigned short)(r >> 16);
}

// bare v_exp_f32: computes 2^x (inputs are pre-scaled by log2(e) at gather)
__device__ inline float exp2fast(float x) {
    float r;
    asm("v_exp_f32 %0, %1" : "=v"(r) : "v"(x));
    return r;
}

// global->LDS direct DMA, 16B/lane; LDS dest = wave-uniform base + lane*16.
__device__ inline void gl_lds16(const unsigned short* g, unsigned short* l) {
    __builtin_amdgcn_global_load_lds(
        reinterpret_cast<__attribute__((address_space(1))) unsigned int*>(
            reinterpret_cast<uintptr_t>(g)),
        reinterpret_cast<__attribute__((address_space(3))) unsigned int*>(
            reinterpret_cast<uintptr_t>(l)),
        16, 0, 0);
}

__device__ inline void wait_vmcnt0() { asm volatile("s_waitcnt vmcnt(0)" ::: "memory"); }
__device__ inline void raw_barrier() { asm volatile("s_barrier" ::: "memory"); }

// DPP 16-lane sum reduction — VALU only.
template<int CTRL>
__device__ inline float dpp_add(float x) {
    int v = __builtin_amdgcn_update_dpp(0, __float_as_int(x), CTRL, 0xF, 0xF, false);
    return x + __int_as_float(v);
}
__device__ inline float red16(float x) {
    x = dpp_add<0xB1>(x);    // quad_perm [1,0,3,2]
    x = dpp_add<0x4E>(x);    // quad_perm [2,3,0,1]
    x = dpp_add<0x141>(x);   // row_half_mirror
    x = dpp_add<0x140>(x);   // row_mirror
    return x;
}

// ---------------------------------------------------------------------------
// Kernel 1: gather + fp32->bf16 convert + fused en_score + denom zero-init.
// E rows are pre-scaled by log2(e) so kernel 2's exp is a bare v_exp_f32.
// z_bf is NOT scaled (kernel 3 consumes it as the B operand).
// ---------------------------------------------------------------------------
__global__ void gather_kernel(
    const float* __restrict__ zs,
    const float* __restrict__ W_en, const float* __restrict__ W_fr,
    const int* __restrict__ pos_en, const int* __restrict__ neg_en,
    const int* __restrict__ pos_fr, const int* __restrict__ neg_fr,
    const int* __restrict__ x_en,
    unsigned short* __restrict__ z_bf,
    unsigned short* __restrict__ E_en, unsigned short* __restrict__ E_fr,
    float* __restrict__ en_score,
    float* __restrict__ denom_en, float* __restrict__ denom_fr,
    int Pe, int Pf, int Lpe, int Lpf)
{
    int row  = blockIdx.x * 4 + (threadIdx.x >> 6);
    int lane = threadIdx.x & 63;
    const float* src = nullptr;
    unsigned short* dst = nullptr;
    bool zero = false;
    float sc = LOG2E;                 // E rows get the log2e pre-scale

    if (row < NTOK) {
        src = zs + (size_t)row * DDIM;
        dst = z_bf + (size_t)row * DDIM;
        sc = 1.0f;                    // z_bf stays unscaled
        if (lane == 0) { denom_en[row] = 0.0f; denom_fr[row] = 0.0f; }
    } else if (row < NTOK + Lpe) {
        int j = row - NTOK;
        int Le = Pe + NEGN;
        int idx = 0;
        if (j < Pe)      idx = pos_en[j];
        else if (j < Le) idx = neg_en[j - Pe];
        else             zero = true;
        src = W_en + (size_t)idx * DDIM;
        dst = E_en + (size_t)j * DDIM;
    } else if (row < NTOK + Lpe + Lpf) {
        int j = row - NTOK - Lpe;
        int Lf = Pf + NEGN;
        int idx = 0;
        if (j < Pf)      idx = pos_fr[j];
        else if (j < Lf) idx = neg_fr[j - Pf];
        else             zero = true;
        src = W_fr + (size_t)idx * DDIM;
        dst = E_fr + (size_t)j * DDIM;
    } else if (row < NTOK + Lpe + Lpf + NTOK) {
        // fused en_score: zs[j] . W_en[x_en[j]] in fp32, wave reduce
        int j = row - NTOK - Lpe - Lpf;
        int idx = x_en[j];
        float4 z = *(const float4*)(zs   + (size_t)j   * DDIM + lane * 4);
        float4 w = *(const float4*)(W_en + (size_t)idx * DDIM + lane * 4);
        float s = z.x * w.x + z.y * w.y + z.z * w.z + z.w * w.w;
        #pragma unroll
        for (int m = 32; m; m >>= 1) s += __shfl_xor(s, m);
        if (lane == 0) en_score[j] = s;
        return;
    } else {
        return;
    }

    int d = lane * 4;
    float4 v;
    if (zero) { v.x = v.y = v.z = v.w = 0.0f; }
    else      { v = *(const float4*)(src + d); }
    ushort4 o;
    o.x = f2bf(v.x * sc); o.y = f2bf(v.y * sc);
    o.z = f2bf(v.z * sc); o.w = f2bf(v.w * sc);
    *(ushort4*)(dst + d) = o;
}

// ---------------------------------------------------------------------------
// Kernel 2: fused denominators — R2 structure (best: 56.4us) + INTRA-WAVE
// MFMA/epilogue interleave. R2/R3 accounting: MFMA 44% + epilogue VALU 32%
// strictly ALTERNATE inside each wave (chunk loop then exp burst) and blocks
// don't de-phase on their own -> ~35% dead cycles. Fix: loop-reorder so acc
// maturity is per-n-frag: sweep full K per n-frag j (1 ds_read + 4 MFMA per
// chunk); acc[:,j] matures at sweep end and DRAINS (2 exp2 + 2 fma per
// chunk) under sweep j+1's MFMAs. Ping-pong accA/accB = 32 acc regs (vs 128
// for tile-level 2-deep) -> ~210 VGPR total, keeps 2 waves/SIMD. Pending j3
// drains under next tile's j0; en->fr flush at the j0/j1 seam (taken once).
// E is pre-scaled by log2e so the drain exp is a bare v_exp_f32.
// Sync protocol per tile unchanged from R2 (own vmcnt(0) -> raw s_barrier),
// HW-verified absmax 0.0.
// Frag layouts (HW-verified): A/B lane holds row (lane&15), 8 k-halfs at
// (lane>>4)*8;  C/D: n-col = lane&15, m-row = (lane>>4)*4 + reg.
// ---------------------------------------------------------------------------
__global__ __launch_bounds__(256, 2) void expsum_stream(
    const unsigned short* __restrict__ A,   // z_bf [4096 x 256]
    const unsigned short* __restrict__ E,   // [Ltot x 256], pre-scaled log2e
    const float* __restrict__ kep, const float* __restrict__ kfp,
    float* __restrict__ out_en, float* __restrict__ out_fr,
    int Pe, int Pf, int Lpe, int NT)        // NT = Ltot/64 n-tiles
{
    // 2 tiles x 8 chunks x 4KB; chunk slab: 4 sub-blocks of 16 rows, each
    // packed lane-linear (lane*16B) for conflict-free DMA write + b128 read.
    __shared__ __align__(16) unsigned short Bs[2][8][2048];

    // 512 blocks: xcd = lin&7, m-tile xb = (lin>>3)&15, slice = xcd + 8*(lin>>7)
    // XCD k streams only tiles ≡ k (mod 8) -> 1/8 of E resident in its L2.
    int lin = blockIdx.y * 64 + blockIdx.x;
    int xcd = lin & 7;
    int xb  = (lin >> 3) & 15;
    int sl  = xcd + 8 * (lin >> 7);    // 0..31; tiles {sl, sl+32, ...}

    int t    = threadIdx.x;
    int lane = t & 63;
    int wave = t >> 6;
    int col  = lane & 15;
    int quad = lane >> 4;

    // kappas: load + pin BEFORE any DMA so the vmcnt queue stays clean
    float ke = kep[0], kf = kfp[0];
    asm volatile("" : "+v"(ke), "+v"(kf) : : "memory");

    // ---- A fragments in registers (one-time load; wave owns 64 m rows)
    bf16x8 afr[4][8];
    {
        const unsigned short* Ap =
            A + ((size_t)(xb * 256 + wave * 64 + col)) * DDIM + quad * 8;
        #pragma unroll
        for (int i = 0; i < 4; i++)
            #pragma unroll
            for (int c = 0; c < 8; c++)
                afr[i][c] = *(const bf16x8*)(Ap + (size_t)i * 16 * DDIM + c * 32);
    }

    float sums[4][4];
    #pragma unroll
    for (int i = 0; i < 4; i++)
        #pragma unroll
        for (int rr = 0; rr < 4; rr++) sums[i][rr] = 0.0f;

    f32x4 accA[4], accB[4];
    #pragma unroll
    for (int i = 0; i < 4; i++) accB[i] = (f32x4){0.f, 0.f, 0.f, 0.f};
    float wjP = 0.0f;                  // weight of the pending (accB) n-frag
    float* curout = out_en;
    int outrow = xb * 256 + wave * 64;

    int ntiles = (NT - sl + 31) >> 5;

    // stage tile s: this wave's 16-row sub-block for ALL 8 k-chunks (8 DMAs).
    #define STAGE_TILE(s) do {                                               \
        int tl_ = sl + ((s) << 5);                                           \
        const unsigned short* g_ =                                           \
            E + (size_t)(tl_ * 64 + wave * 16 + col) * DDIM + quad * 8;      \
        unsigned short* l_ = &Bs[(s) & 1][0][wave * 512];                    \
        _Pragma("unroll")                                                    \
        for (int kc_ = 0; kc_ < 8; kc_++)                                    \
            gl_lds16(g_ + kc_ * 32, l_ + kc_ * 2048);                        \
    } while (0)

    // full-K sweep for n-frag J: compute ACCC; drain ACCD (weight WJD) under
    // the MFMAs, 2 entries per chunk (16 entries over 8 chunks).
    #define J_SWEEP(J, ACCC, ACCD, WJD) do {                                 \
        _Pragma("unroll")                                                    \
        for (int i = 0; i < 4; i++) ACCC[i] = (f32x4){0.f, 0.f, 0.f, 0.f};   \
        _Pragma("unroll")                                                    \
        for (int k8 = 0; k8 < 8; k8++) {                                     \
            bf16x8 bfv = *(const bf16x8*)(                                   \
                &Bs[s & 1][k8][(J) * 512 + quad * 128 + col * 8]);           \
            _Pragma("unroll")                                                \
            for (int i = 0; i < 4; i++)                                      \
                ACCC[i] = __builtin_amdgcn_mfma_f32_16x16x32_bf16(           \
                    afr[i][k8], bfv, ACCC[i], 0, 0, 0);                      \
            sums[(k8 * 2) >> 2][(k8 * 2) & 3] +=                             \
                (WJD) * exp2fast(ACCD[(k8 * 2) >> 2][(k8 * 2) & 3]);         \
            sums[(k8 * 2 + 1) >> 2][(k8 * 2 + 1) & 3] +=                     \
                (WJD) * exp2fast(ACCD[(k8 * 2 + 1) >> 2][(k8 * 2 + 1) & 3]); \
        }                                                                    \
    } while (0)

    #define FLUSH_SUMS() do {                                                \
        _Pragma("unroll")                                                    \
        for (int i = 0; i < 4; i++)                                          \
            _Pragma("unroll")                                                \
            for (int rr = 0; rr < 4; rr++) {                                 \
                float v = red16(sums[i][rr]);                                \
                if (col == 0)                                                \
                    atomicAdd(curout + outrow + 16 * i + quad * 4 + rr, v);  \
                sums[i][rr] = 0.0f;                                          \
            }                                                                \
    } while (0)

    STAGE_TILE(0);

    for (int s = 0; s < ntiles; s++) {
        int tl = sl + (s << 5);
        int nb = tl * 64;

        wait_vmcnt0();      // my tile-s DMAs retired (issued 1 tile-period ago)
        raw_barrier();      // all waves' tile-s resident; all done reading s-1

        if (s + 1 < ntiles) STAGE_TILE(s + 1);   // 8 DMAs, fly under compute

        // arithmetic weights: n < P -> 1 ; n < P+NEGN -> kappa ; else 0 (pad)
        float wj[4];
        #pragma unroll
        for (int j = 0; j < 4; j++) {
            int ngl = nb + 16 * j + col;
            if (nb < Lpe) {
                wj[j] = (ngl < Pe) ? 1.0f : ((ngl < Pe + NEGN) ? ke : 0.0f);
            } else {
                int nl = ngl - Lpe;
                wj[j] = (nl < Pf) ? 1.0f : ((nl < Pf + NEGN) ? kf : 0.0f);
            }
        }
        float* outC = (nb >= Lpe) ? out_fr : out_en;

        // j0: drains the pending frag (prev tile's j3, weight wjP, out curout)
        J_SWEEP(0, accA, accB, wjP);
        if (outC != curout) {          // en->fr boundary: taken once per block
            FLUSH_SUMS();
            curout = outC;
        }
        J_SWEEP(1, accB, accA, wj[0]);
        J_SWEEP(2, accA, accB, wj[1]);
        J_SWEEP(3, accB, accA, wj[2]);
        wjP = wj[3];                   // accB (j3) pends into the next tile
    }
    #undef STAGE_TILE
    #undef J_SWEEP

    // drain the final pending frag, then flush
    #pragma unroll
    for (int i = 0; i < 4; i++)
        #pragma unroll
        for (int rr = 0; rr < 4; rr++)
            sums[i][rr] += wjP * exp2fast(accB[i][rr]);
    FLUSH_SUMS();
    #undef FLUSH_SUMS
}

// ---------------------------------------------------------------------------
// Kernel 3: fr alignment (per-batch 64x64 exp-sum, weight 1/denom_fr) with
// inline W_fr[x_fr] gather+convert for A (pre-scaled by log2e -> bare
// v_exp_f32) and the final loss fused in.
// ---------------------------------------------------------------------------
__global__ __launch_bounds__(256) void expsum_gemm64_loss(
    const float* __restrict__ W_fr,         // [V_FR x 256] fp32
    const int* __restrict__ x_fr,           // [B*64]
    const unsigned short* __restrict__ Bm,  // z_bf  [B][64 x 256]
    const float* __restrict__ denom_fr,     // [B*64]
    const float* __restrict__ denom_en,     // [B*64]
    const float* __restrict__ en_score,     // [B*64]
    const float* __restrict__ en_mask,
    const float* __restrict__ fr_mask,
    float* __restrict__ outloss)            // [128]: en | fr
{
    __shared__ __align__(16) unsigned short lda[TM * LDT];
    __shared__ __align__(16) unsigned short ldb[TN * LDT];
    __shared__ float tbuf[64];

    int batch = blockIdx.x;
    const unsigned short* Bb = Bm + (size_t)batch * TN * DDIM;

    int t      = threadIdx.x;
    int srow   = t >> 2;
    int schunk = t & 3;
    int lane   = t & 63;
    int wave   = t >> 6;
    int col    = lane & 15;
    int quad   = lane >> 4;

    int aidx = x_fr[batch * 64 + srow];
    const float* Arow = W_fr + (size_t)aidx * DDIM;

    f32x4 acc0 = {0.f,0.f,0.f,0.f};
    f32x4 acc1 = {0.f,0.f,0.f,0.f};
    f32x4 acc2 = {0.f,0.f,0.f,0.f};
    f32x4 acc3 = {0.f,0.f,0.f,0.f};

    for (int kk = 0; kk < DDIM; kk += 32) {
        float4 f0 = *(const float4*)(Arow + kk + schunk * 8);
        float4 f1 = *(const float4*)(Arow + kk + schunk * 8 + 4);
        uint4 bv = *(const uint4*)(Bb + (size_t)srow * DDIM + kk + schunk * 8);
        ushort4 ua; ua.x = f2bf(f0.x * LOG2E); ua.y = f2bf(f0.y * LOG2E);
                    ua.z = f2bf(f0.z * LOG2E); ua.w = f2bf(f0.w * LOG2E);
        ushort4 ub; ub.x = f2bf(f1.x * LOG2E); ub.y = f2bf(f1.y * LOG2E);
                    ub.z = f2bf(f1.z * LOG2E); ub.w = f2bf(f1.w * LOG2E);
        __syncthreads();
        *(ushort4*)(lda + srow * LDT + schunk * 8)     = ua;
        *(ushort4*)(lda + srow * LDT + schunk * 8 + 4) = ub;
        *(uint4*)(ldb + srow * LDT + schunk * 8) = bv;
        __syncthreads();

        bf16x8 af = *(const bf16x8*)(lda + (wave * 16 + col) * LDT + quad * 8);
        bf16x8 b0 = *(const bf16x8*)(ldb + ( 0 + col) * LDT + quad * 8);
        bf16x8 b1 = *(const bf16x8*)(ldb + (16 + col) * LDT + quad * 8);
        bf16x8 b2 = *(const bf16x8*)(ldb + (32 + col) * LDT + quad * 8);
        bf16x8 b3 = *(const bf16x8*)(ldb + (48 + col) * LDT + quad * 8);
        acc0 = __builtin_amdgcn_mfma_f32_16x16x32_bf16(af, b0, acc0, 0, 0, 0);
        acc1 = __builtin_amdgcn_mfma_f32_16x16x32_bf16(af, b1, acc1, 0, 0, 0);
        acc2 = __builtin_amdgcn_mfma_f32_16x16x32_bf16(af, b2, acc2, 0, 0, 0);
        acc3 = __builtin_amdgcn_mfma_f32_16x16x32_bf16(af, b3, acc3, 0, 0, 0);
    }

    const float* db = denom_fr + batch * 64;
    float w0 = 1.0f / db[ 0 + col];
    float w1 = 1.0f / db[16 + col];
    float w2 = 1.0f / db[32 + col];
    float w3 = 1.0f / db[48 + col];

    float tot0 = w0 * exp2fast(acc0.x) + w1 * exp2fast(acc1.x) + w2 * exp2fast(acc2.x) + w3 * exp2fast(acc3.x);
    float tot1 = w0 * exp2fast(acc0.y) + w1 * exp2fast(acc1.y) + w2 * exp2fast(acc2.y) + w3 * exp2fast(acc3.y);
    float tot2 = w0 * exp2fast(acc0.z) + w1 * exp2fast(acc1.z) + w2 * exp2fast(acc2.z) + w3 * exp2fast(acc3.z);
    float tot3 = w0 * exp2fast(acc0.w) + w1 * exp2fast(acc1.w) + w2 * exp2fast(acc2.w) + w3 * exp2fast(acc3.w);

    #pragma unroll
    for (int m = 1; m < 16; m <<= 1) {
        tot0 += __shfl_xor(tot0, m);
        tot1 += __shfl_xor(tot1, m);
        tot2 += __shfl_xor(tot2, m);
        tot3 += __shfl_xor(tot3, m);
    }
    if (col == 0) {
        int base = wave * 16 + quad * 4;
        tbuf[base + 0] = tot0; tbuf[base + 1] = tot1;
        tbuf[base + 2] = tot2; tbuf[base + 3] = tot3;
    }
    __syncthreads();

    if (t < 64) {
        int i = batch * 64 + t;
        float a = (en_score[i] - __logf(denom_en[i])) * en_mask[i];
        float c = __logf(tbuf[t]) * fr_mask[i];
        #pragma unroll
        for (int m = 32; m; m >>= 1) { a += __shfl_xor(a, m); c += __shfl_xor(c, m); }
        if (t == 0) { outloss[batch] = a; outloss[64 + batch] = c; }
    }
}

extern "C" void kernel_launch(void* const* d_in, const int* in_sizes, int n_in,
                              void* d_out, int out_size, void* d_ws, size_t ws_size,
                              hipStream_t stream)
{
    const float* zs       = (const float*)d_in[0];
    const int*   x_en     = (const int*)d_in[1];
    const int*   x_fr     = (const int*)d_in[2];
    const float* en_mask  = (const float*)d_in[3];
    const float* fr_mask  = (const float*)d_in[4];
    const float* W_en     = (const float*)d_in[5];
    const float* W_fr     = (const float*)d_in[6];
    const int*   pos_en   = (const int*)d_in[7];
    const int*   neg_en   = (const int*)d_in[8];
    const int*   pos_fr   = (const int*)d_in[9];
    const int*   neg_fr   = (const int*)d_in[10];
    const float* kappa_en = (const float*)d_in[11];
    const float* kappa_fr = (const float*)d_in[12];

    int Pe  = in_sizes[7];
    int Pf  = in_sizes[9];
    int Lpe = (Pe + NEGN + 63) & ~63;     // 64-aligned n-tiles (no straddle)
    int Lpf = (Pf + NEGN + 63) & ~63;
    int Ltot = Lpe + Lpf;
    int NT   = Ltot / 64;

    char* w = (char*)d_ws;
    float* denom_en = (float*)w; w += NTOK * 4;
    float* denom_fr = (float*)w; w += NTOK * 4;
    float* en_score = (float*)w; w += NTOK * 4;
    unsigned short* z_bf  = (unsigned short*)w; w += (size_t)NTOK * DDIM * 2;
    unsigned short* E_all = (unsigned short*)w; w += (size_t)Ltot * DDIM * 2;

    int totrows = NTOK + Lpe + Lpf + NTOK;
    gather_kernel<<<(totrows + 3) / 4, 256, 0, stream>>>(
        zs, W_en, W_fr, pos_en, neg_en, pos_fr, neg_fr, x_en,
        z_bf, E_all, E_all + (size_t)Lpe * DDIM,
        en_score, denom_en, denom_fr, Pe, Pf, Lpe, Lpf);

    // fused denominators: R2 structure + intra-wave MFMA/epilogue interleave
    expsum_stream<<<dim3(64, 8), 256, 0, stream>>>(
        z_bf, E_all, kappa_en, kappa_fr, denom_en, denom_fr, Pe, Pf, Lpe, NT);

    // fr alignment + inline W_fr gather (log2e-scaled) + fused loss
    expsum_gemm64_loss<<<64, 256, 0, stream>>>(
        W_fr, x_fr, z_bf, denom_fr, denom_en, en_score, en_mask, fr_mask,
        (float*)d_out);
}